// Round 2
// baseline (23943.427 us; speedup 1.0000x reference)
//
#include <hip/hip_runtime.h>
#include <math.h>

// LSTM: x[64][512][512] fp32, W[1024][2048] fp32, b[2048] fp32 -> out[64][512][512]
// z = [h,x_t] @ W + b ; f,i,o,cb = split(z,4); c' = sig(f)c + sig(i)cb ; h' = sig(o)c'
//
// Persistent-kernel design: 256 blocks (cg 0..63 x sg 0..3), 1 block/CU.
// Block owns 32 z-cols (8 h-cols x 4 gates) x 16 seqs. W slice (1024x32 fp32,
// 128 KB) lives in LDS for the whole kernel. h passes between steps via a
// double-buffered global array; manual device-scope grid barrier per step.
// c-state is per-thread registers. A=[h|x_t] staged in a 2-buffer LDS pipeline.

#define APAD 132           // A chunk row stride (floats)
#define HBUF_FLOATS (64*512)
#define WB_FLOATS   (64*1024*32)

__global__ __launch_bounds__(256) void zero_ws(float* __restrict__ p, int n) {
    int i = blockIdx.x * 256 + threadIdx.x;
    if (i < n) p[i] = 0.0f;
}

// Wb[cg][k][c] = W[k][g*512 + cg*8 + hc], c = g*8+hc
__global__ __launch_bounds__(256) void prep_w(const float* __restrict__ W,
                                              float* __restrict__ Wb) {
    int k = blockIdx.x;  // 0..1023
    for (int it = 0; it < 8; ++it) {
        int col = it * 256 + threadIdx.x;          // 0..2047
        float v = W[(size_t)k * 2048 + col];
        int g = col >> 9, rem = col & 511;
        int cg = rem >> 3, hc = rem & 7;
        Wb[((size_t)cg * 1024 + k) * 32 + g * 8 + hc] = v;
    }
}

__global__ __launch_bounds__(256, 1) void lstm_persist(
    const float* __restrict__ x,      // [64][512][512]
    const float* __restrict__ bias,   // [2048]
    const float* __restrict__ Wb,     // [64][1024][32]
    float* __restrict__ hbuf,         // [2][64][512]
    unsigned* __restrict__ bar,       // grid barrier counter (zeroed)
    float* __restrict__ out)          // [64][512][512]
{
    __shared__ float Ws[32768];          // 128 KB W slice
    __shared__ float As[2][16 * APAD];   // 2 x 8.25 KB A chunk double buffer
    __shared__ float zred[512];
    float* const zpart = &As[0][0];      // aliases As (4096 <= 4224 floats)

    const int tid = threadIdx.x;
    const int cg  = blockIdx.x & 63;
    const int sg  = blockIdx.x >> 6;

    // ---- load W slice into LDS (once) ----
    {
        const float* wsrc = Wb + (size_t)cg * 32768;
        for (int i = 0; i < 32; ++i) {
            int fi = (i * 256 + tid) * 4;
            *(float4*)(Ws + fi) = *(const float4*)(wsrc + fi);
        }
    }

    // GEMM thread coords: 4s x 4c register tile, K split 8-ways
    const int ct = tid & 7;
    const int st = (tid >> 3) & 3;
    const int kw = tid >> 5;

    // staging coords: thread stages rows s0 and s0+8, float4 column f40
    const int s0  = tid >> 5;
    const int f40 = tid & 31;

    // epilogue coords + bias preload + c register state
    const int es = tid >> 3, ehc = tid & 7;
    float bf = 0, bi = 0, bo = 0, bc = 0;
    if (tid < 128) {
        int colb = cg * 8 + ehc;
        bf = bias[colb];
        bi = bias[512 + colb];
        bo = bias[1024 + colb];
        bc = bias[1536 + colb];
    }
    float creg = 0.0f;

    __syncthreads();  // Ws ready

    unsigned target = 0;
    for (int t = 0; t < 512; ++t) {
        const float* hr = hbuf + (t & 1) * HBUF_FLOATS;
        float*       hw = hbuf + ((t + 1) & 1) * HBUF_FLOATS;

        float acc[4][4];
#pragma unroll
        for (int i = 0; i < 4; ++i)
#pragma unroll
            for (int j = 0; j < 4; ++j) acc[i][j] = 0.0f;

        // ---- stage chunk 0 (h cols 0..127) ----
        {
            float4 v0 = *(const float4*)(hr + (sg * 16 + s0) * 512 + f40 * 4);
            float4 v1 = *(const float4*)(hr + (sg * 16 + s0 + 8) * 512 + f40 * 4);
            *(float4*)(&As[0][s0 * APAD + f40 * 4]) = v0;
            *(float4*)(&As[0][(s0 + 8) * APAD + f40 * 4]) = v1;
        }
        __syncthreads();

        // ---- 8 K-chunks of 128, software-pipelined ----
        for (int ch = 0; ch < 8; ++ch) {
            float4 p0, p1;
            if (ch < 7) {
                int kb = (ch + 1) * 128 + f40 * 4;   // global k of prefetch
                const float *src0, *src1;
                if (kb < 512) {
                    src0 = hr + (sg * 16 + s0) * 512 + kb;
                    src1 = hr + (sg * 16 + s0 + 8) * 512 + kb;
                } else {
                    src0 = x + ((size_t)(sg * 16 + s0) * 512 + t) * 512 + (kb - 512);
                    src1 = x + ((size_t)(sg * 16 + s0 + 8) * 512 + t) * 512 + (kb - 512);
                }
                p0 = *(const float4*)src0;
                p1 = *(const float4*)src1;
            }

            const float* ap = &As[ch & 1][st * 4 * APAD + kw * 16];
            const float* wp = Ws + (ch * 128 + kw * 16) * 32 + ct * 4;
#pragma unroll
            for (int kk = 0; kk < 16; kk += 4) {
                float4 w0 = *(const float4*)(wp + (kk + 0) * 32);
                float4 w1 = *(const float4*)(wp + (kk + 1) * 32);
                float4 w2 = *(const float4*)(wp + (kk + 2) * 32);
                float4 w3 = *(const float4*)(wp + (kk + 3) * 32);
                float4 a0 = *(const float4*)(ap + 0 * APAD + kk);
                float4 a1 = *(const float4*)(ap + 1 * APAD + kk);
                float4 a2 = *(const float4*)(ap + 2 * APAD + kk);
                float4 a3 = *(const float4*)(ap + 3 * APAD + kk);
#define FMA_ROW(i, ai)                                                      \
                acc[i][0] += ai.x * w0.x + ai.y * w1.x + ai.z * w2.x + ai.w * w3.x; \
                acc[i][1] += ai.x * w0.y + ai.y * w1.y + ai.z * w2.y + ai.w * w3.y; \
                acc[i][2] += ai.x * w0.z + ai.y * w1.z + ai.z * w2.z + ai.w * w3.z; \
                acc[i][3] += ai.x * w0.w + ai.y * w1.w + ai.z * w2.w + ai.w * w3.w;
                FMA_ROW(0, a0)
                FMA_ROW(1, a1)
                FMA_ROW(2, a2)
                FMA_ROW(3, a3)
#undef FMA_ROW
            }

            if (ch < 7) {
                float* dst = &As[(ch + 1) & 1][0];
                *(float4*)(dst + s0 * APAD + f40 * 4) = p0;
                *(float4*)(dst + (s0 + 8) * APAD + f40 * 4) = p1;
            }
            __syncthreads();
        }

        // ---- K-partial write + 8-way reduce (zpart aliases As, safe after sync) ----
#pragma unroll
        for (int i = 0; i < 4; ++i) {
            *(float4*)(zpart + kw * 512 + (st * 4 + i) * 32 + ct * 4) =
                make_float4(acc[i][0], acc[i][1], acc[i][2], acc[i][3]);
        }
        __syncthreads();
        {
            int o = tid * 2;
            float z0 = 0.0f, z1 = 0.0f;
#pragma unroll
            for (int w = 0; w < 8; ++w) {
                float2 v = *(const float2*)(zpart + w * 512 + o);
                z0 += v.x; z1 += v.y;
            }
            *(float2*)(zred + o) = make_float2(z0, z1);
        }
        __syncthreads();

        // ---- epilogue: gates + state update ----
        if (tid < 128) {
            float zf = zred[es * 32 + ehc]      + bf;
            float zi = zred[es * 32 + 8 + ehc]  + bi;
            float zo = zred[es * 32 + 16 + ehc] + bo;
            float zc = zred[es * 32 + 24 + ehc] + bc;
            float sf = 1.0f / (1.0f + expf(-zf));
            float si = 1.0f / (1.0f + expf(-zi));
            float so = 1.0f / (1.0f + expf(-zo));
            creg = sf * creg + si * zc;
            float h = so * creg;
            int colb = cg * 8 + ehc;
            hw[(sg * 16 + es) * 512 + colb] = h;
            out[((size_t)(sg * 16 + es) * 512 + t) * 512 + colb] = h;
        }

        // ---- device-scope grid barrier ----
        target += 256;
        __threadfence();       // release: flush h stores device-wide
        __syncthreads();
        if (tid == 0) {
            __hip_atomic_fetch_add(bar, 1u, __ATOMIC_RELEASE, __HIP_MEMORY_SCOPE_AGENT);
            while (__hip_atomic_load(bar, __ATOMIC_ACQUIRE, __HIP_MEMORY_SCOPE_AGENT) < target)
                __builtin_amdgcn_s_sleep(1);
            __threadfence();   // acquire: invalidate stale cache lines
        }
        __syncthreads();
    }
}

extern "C" void kernel_launch(void* const* d_in, const int* in_sizes, int n_in,
                              void* d_out, int out_size, void* d_ws, size_t ws_size,
                              hipStream_t stream) {
    const float* x    = (const float*)d_in[0];
    const float* W    = (const float*)d_in[1];
    const float* bias = (const float*)d_in[2];
    float* out = (float*)d_out;

    char* ws = (char*)d_ws;
    float* Wb       = (float*)ws;
    float* hbuf     = (float*)(ws + (size_t)WB_FLOATS * 4);
    unsigned* bar   = (unsigned*)(hbuf + 2 * HBUF_FLOATS);

    // zero h double-buffer + barrier counter (ws is poisoned 0xAA each call)
    zero_ws<<<257, 256, 0, stream>>>(hbuf, 2 * HBUF_FLOATS + 256);
    prep_w<<<1024, 256, 0, stream>>>(W, Wb);
    lstm_persist<<<256, 256, 0, stream>>>(x, bias, Wb, hbuf, bar, out);
}